// Round 3
// baseline (953.426 us; speedup 1.0000x reference)
//
#include <hip/hip_runtime.h>

#define B_ 32
#define C_ 256
#define T_ 2048
#define N_ 65536      // B_*T_
#define NE_ 1024
#define NELEM 16777216  // B_*C_*T_
#define TAU 1.2e-4f     // repair window: covers np's fp32 quantization (~3e-5/score) + GEMM err
#define WLCAP 16384

// d_ws layout (4-byte units):
// [0,1024)        counts (int)
// [1024,2048)     enorm (float, fl32 of fp64-exact ||e||^2)
// [2048]          sse (float)
// [2049]          nflag (int)
// [4608,70144)    idx (int)
// [70144,86528)   worklist (int)

__global__ void k_enorm(const float* __restrict__ emb, float* __restrict__ enorm) {
  int j = blockIdx.x * blockDim.x + threadIdx.x;
  const float4* row = reinterpret_cast<const float4*>(emb + (size_t)j * C_);
  double s = 0.0;
#pragma unroll
  for (int k = 0; k < C_ / 4; ++k) {
    float4 v = row[k];
    s = fma((double)v.x, (double)v.x, s);
    s = fma((double)v.y, (double)v.y, s);
    s = fma((double)v.z, (double)v.z, s);
    s = fma((double)v.w, (double)v.w, s);
  }
  enorm[j] = (float)s;
}

#define TM 64
#define TN 128
#define BK 32

__launch_bounds__(256, 2)
__global__ void k_vq(const float* __restrict__ z, const float* __restrict__ emb,
                     const float* __restrict__ enorm, int* __restrict__ idx_i,
                     float* __restrict__ idx_f, int* __restrict__ nflag,
                     int* __restrict__ worklist) {
  __shared__ float As[C_ * TM];  // [k][row], 64 KB
  __shared__ float Bs[BK * TN];  // [k][code], 16 KB
  const int tid = threadIdx.x;
  const int n0 = blockIdx.x * TM;
  const int bb = n0 >> 11;
  const int t0 = n0 & (T_ - 1);
  const float* zbase = z + (size_t)bb * C_ * T_ + t0;
  const int lt = tid & 63;
  {
    int c = tid >> 6;
#pragma unroll 4
    for (; c < C_; c += 4)
      As[c * TM + lt] = zbase[(size_t)c * T_ + lt];
  }

  const int rg = (tid >> 4) << 2;  // row base within tile
  const int cg = (tid & 15) << 3;  // code base within stripe

  float b1s[4]; int b1i[4]; float b2s[4];
#pragma unroll
  for (int i = 0; i < 4; ++i) { b1s[i] = 3.4e38f; b2s[i] = 3.4e38f; b1i[i] = 0; }

  for (int s = 0; s < NE_ / TN; ++s) {
    const int c0 = s * TN;
    float acc[4][8];
#pragma unroll
    for (int i = 0; i < 4; ++i)
#pragma unroll
      for (int j = 0; j < 8; ++j) acc[i][j] = 0.f;

    for (int kc = 0; kc < C_; kc += BK) {
      __syncthreads();
      {
        const int code = tid >> 1;
        const int h = tid & 1;
        const float4* src = reinterpret_cast<const float4*>(
            emb + (size_t)(c0 + code) * C_ + kc + h * 16);
#pragma unroll
        for (int q = 0; q < 4; ++q) {
          float4 v = src[q];
          int kk = h * 16 + q * 4;
          Bs[(kk + 0) * TN + code] = v.x;
          Bs[(kk + 1) * TN + code] = v.y;
          Bs[(kk + 2) * TN + code] = v.z;
          Bs[(kk + 3) * TN + code] = v.w;
        }
      }
      __syncthreads();
#pragma unroll
      for (int k = 0; k < BK; ++k) {
        const float4 av = *reinterpret_cast<const float4*>(&As[(kc + k) * TM + rg]);
        const float4 b0 = *reinterpret_cast<const float4*>(&Bs[k * TN + cg]);
        const float4 b1 = *reinterpret_cast<const float4*>(&Bs[k * TN + cg + 4]);
        const float a_[4] = {av.x, av.y, av.z, av.w};
        const float b_[8] = {b0.x, b0.y, b0.z, b0.w, b1.x, b1.y, b1.z, b1.w};
#pragma unroll
        for (int i = 0; i < 4; ++i)
#pragma unroll
          for (int j = 0; j < 8; ++j)
            acc[i][j] = fmaf(a_[i], b_[j], acc[i][j]);
      }
    }
    float en[8];
    *reinterpret_cast<float4*>(&en[0]) =
        *reinterpret_cast<const float4*>(&enorm[c0 + cg]);
    *reinterpret_cast<float4*>(&en[4]) =
        *reinterpret_cast<const float4*>(&enorm[c0 + cg + 4]);
#pragma unroll
    for (int j = 0; j < 8; ++j) {
#pragma unroll
      for (int i = 0; i < 4; ++i) {
        float sc = fmaf(-2.f, acc[i][j], en[j]);
        if (sc < b1s[i]) { b2s[i] = b1s[i]; b1s[i] = sc; b1i[i] = c0 + cg + j; }
        else if (sc < b2s[i]) b2s[i] = sc;
      }
    }
  }
#pragma unroll
  for (int m = 1; m < 16; m <<= 1) {
#pragma unroll
    for (int i = 0; i < 4; ++i) {
      float o1s = __shfl_xor(b1s[i], m);
      int o1i = __shfl_xor(b1i[i], m);
      float o2s = __shfl_xor(b2s[i], m);
      float hi = fmaxf(b1s[i], o1s);
      b2s[i] = fminf(fminf(b2s[i], o2s), hi);
      if (o1s < b1s[i] || (o1s == b1s[i] && o1i < b1i[i])) { b1s[i] = o1s; b1i[i] = o1i; }
    }
  }
  if ((tid & 15) == 0) {
#pragma unroll
    for (int i = 0; i < 4; ++i) {
      int n = n0 + rg + i;
      idx_i[n] = b1i[i];
      idx_f[n] = (float)b1i[i];
      if (b2s[i] - b1s[i] < TAU) {
        int p = atomicAdd(nflag, 1);
        if (p < WLCAP) worklist[p] = n;
      }
    }
  }
}

// Re-score flagged rows emulating numpy's fp32 arithmetic:
//   d_j = fl32( fl32(sz + se_j) - fl32(2 * dot_j) ),  dot_j via sequential fp32 FMA
// then argmin with lowest-index tie-break (np.argmin first-occurrence).
__global__ void k_repair(const float* __restrict__ z, const float* __restrict__ emb,
                         const float* __restrict__ enorm,
                         const int* __restrict__ nflag, const int* __restrict__ worklist,
                         int* __restrict__ idx_i, float* __restrict__ idx_f) {
  __shared__ float zs[C_];
  __shared__ float szf_s;
  __shared__ double wred[4];
  __shared__ float rs[256];
  __shared__ int ri[256];
  int cnt = nflag[0];
  if (cnt > WLCAP) cnt = WLCAP;
  for (int w = blockIdx.x; w < cnt; w += gridDim.x) {
    int n = worklist[w];
    int b = n >> 11, t = n & (T_ - 1);
    float zv = z[(size_t)b * C_ * T_ + (size_t)threadIdx.x * T_ + t];
    zs[threadIdx.x] = zv;
    double p = (double)zv * (double)zv;
#pragma unroll
    for (int m = 32; m > 0; m >>= 1) p += __shfl_down(p, m);
    if ((threadIdx.x & 63) == 0) wred[threadIdx.x >> 6] = p;
    __syncthreads();
    if (threadIdx.x == 0)
      szf_s = (float)(wred[0] + wred[1] + wred[2] + wred[3]);
    __syncthreads();
    const float szf = szf_s;
    float bd = 3.4e38f; int bi = 1 << 30;
#pragma unroll
    for (int rep = 0; rep < 4; ++rep) {
      int j = rep * 256 + threadIdx.x;  // ascending within thread
      const float4* er = reinterpret_cast<const float4*>(emb + (size_t)j * C_);
      float acc = 0.f;
#pragma unroll 8
      for (int k4 = 0; k4 < C_ / 4; ++k4) {
        float4 ev = er[k4];
        acc = fmaf(zs[k4 * 4 + 0], ev.x, acc);
        acc = fmaf(zs[k4 * 4 + 1], ev.y, acc);
        acc = fmaf(zs[k4 * 4 + 2], ev.z, acc);
        acc = fmaf(zs[k4 * 4 + 3], ev.w, acc);
      }
      float X = szf + enorm[j];
      float Y = 2.0f * acc;
      float d = X - Y;
      if (d < bd || (d == bd && j < bi)) { bd = d; bi = j; }
    }
    rs[threadIdx.x] = bd; ri[threadIdx.x] = bi;
    __syncthreads();
    for (int o = 128; o > 0; o >>= 1) {
      if (threadIdx.x < o) {
        float os = rs[threadIdx.x + o]; int oi = ri[threadIdx.x + o];
        if (os < rs[threadIdx.x] || (os == rs[threadIdx.x] && oi < ri[threadIdx.x])) {
          rs[threadIdx.x] = os; ri[threadIdx.x] = oi;
        }
      }
      __syncthreads();
    }
    if (threadIdx.x == 0) { idx_i[n] = ri[0]; idx_f[n] = (float)ri[0]; }
    __syncthreads();
  }
}

__global__ void k_count(const int* __restrict__ idx_i, int* __restrict__ counts) {
  int n = blockIdx.x * blockDim.x + threadIdx.x;
  atomicAdd(&counts[idx_i[n]], 1);
}

__global__ void k_gather(const float* __restrict__ z, const float* __restrict__ emb,
                         const int* __restrict__ idxv, float* __restrict__ zq,
                         float* __restrict__ sse) {
  int gid = blockIdx.x * blockDim.x + threadIdx.x;
  int i = gid << 2;
  int t = i & (T_ - 1);
  int bc = i >> 11;
  int c = bc & (C_ - 1);
  int b = bc >> 8;
  int n = (b << 11) + t;
  int4 id = *reinterpret_cast<const int4*>(&idxv[n]);
  float4 zv = *reinterpret_cast<const float4*>(&z[i]);
  float4 q;
  q.x = emb[id.x * C_ + c];
  q.y = emb[id.y * C_ + c];
  q.z = emb[id.z * C_ + c];
  q.w = emb[id.w * C_ + c];
  *reinterpret_cast<float4*>(&zq[i]) = q;
  float dx = q.x - zv.x, dy = q.y - zv.y, dz = q.z - zv.z, dw = q.w - zv.w;
  float local = dx * dx + dy * dy + dz * dz + dw * dw;
#pragma unroll
  for (int m = 32; m > 0; m >>= 1) local += __shfl_down(local, m);
  __shared__ float wsum[4];
  if ((threadIdx.x & 63) == 0) wsum[threadIdx.x >> 6] = local;
  __syncthreads();
  if (threadIdx.x == 0) atomicAdd(sse, wsum[0] + wsum[1] + wsum[2] + wsum[3]);
}

__global__ void k_final(const int* __restrict__ counts, const float* __restrict__ sse,
                        float* __restrict__ out_loss, float* __restrict__ out_perp) {
  __shared__ float red[256];
  int tid = threadIdx.x;
  float s = 0.f;
  for (int j = tid; j < NE_; j += 256) {
    float em = (float)counts[j] * (1.0f / (float)N_);
    s += em * logf(em + 1e-10f);
  }
  red[tid] = s;
  __syncthreads();
  for (int o = 128; o > 0; o >>= 1) {
    if (tid < o) red[tid] += red[tid + o];
    __syncthreads();
  }
  if (tid == 0) {
    out_perp[0] = expf(-red[0]);
    out_loss[0] = (0.25f + 1.0f) * sse[0] / (float)NELEM;
  }
}

extern "C" void kernel_launch(void* const* d_in, const int* in_sizes, int n_in,
                              void* d_out, int out_size, void* d_ws, size_t ws_size,
                              hipStream_t stream) {
  const float* z = (const float*)d_in[0];
  const float* emb = (const float*)d_in[1];
  float* out = (float*)d_out;
  float* zq_out = out;
  float* out_loss = out + NELEM;
  float* out_perp = out + NELEM + 1;
  float* out_idx = out + NELEM + 2;

  int* ws_counts = (int*)d_ws;
  float* ws_enorm = (float*)d_ws + 1024;
  float* ws_sse = (float*)d_ws + 2048;
  int* ws_nflag = (int*)d_ws + 2049;
  int* ws_idx = (int*)d_ws + 4608;
  int* ws_worklist = (int*)d_ws + 70144;

  // zero counts + sse + nflag
  hipMemsetAsync(d_ws, 0, 8224, stream);

  k_enorm<<<NE_ / 256, 256, 0, stream>>>(emb, ws_enorm);
  k_vq<<<N_ / TM, 256, 0, stream>>>(z, emb, ws_enorm, ws_idx, out_idx,
                                    ws_nflag, ws_worklist);
  k_repair<<<2048, 256, 0, stream>>>(z, emb, ws_enorm, ws_nflag, ws_worklist,
                                     ws_idx, out_idx);
  k_count<<<N_ / 256, 256, 0, stream>>>(ws_idx, ws_counts);
  k_gather<<<NELEM / 4 / 256, 256, 0, stream>>>(z, emb, ws_idx, zq_out, ws_sse);
  k_final<<<1, 256, 0, stream>>>(ws_counts, ws_sse, out_loss, out_perp);
}

// Round 4
// 647.606 us; speedup vs baseline: 1.4722x; 1.4722x over previous
//
#include <hip/hip_runtime.h>

#define B_ 32
#define C_ 256
#define T_ 2048
#define N_ 65536      // B_*T_
#define NE_ 1024
#define NELEM 16777216  // B_*C_*T_
#define TAU 1.75e-4f    // repair window: np fp32 quantization (~3.2e-5) + f16-split GEMM noise (~4e-5), 2x margin
#define WLCAP 16384

typedef _Float16 half8 __attribute__((ext_vector_type(8)));
typedef float f32x16 __attribute__((ext_vector_type(16)));

// d_ws layout (4-byte units):
// [0,1024)        counts (int)
// [1024,2048)     enorm (float, fl32 of fp64-exact ||e||^2)
// [2048]          sse (float)
// [2049]          nflag (int)
// [4608,70144)    idx (int)
// [70144,86528)   worklist (int)
// [98304,229376)  ebuf: e as f16 in MFMA B-fragment order (512 KB)

// Pre-arrange e -> f16 fragments + fp64-exact ||e||^2.
// B-frag map (consistent with A-frag map in k_vq; any consistent bijection is correct):
//   frag chunk (nt, s) holds B[k = 8*h2 + i][col = nt*32 + lcol] at
//   ebuf[(nt*16 + s)*64 + h2*32 + lcol][i],  k-step s covers c = 16s..16s+15.
__global__ void k_prep(const float* __restrict__ emb, half8* __restrict__ ebuf,
                       float* __restrict__ enorm) {
  int code = blockIdx.x * blockDim.x + threadIdx.x;  // 0..1023
  const float4* row = reinterpret_cast<const float4*>(emb + (size_t)code * C_);
  double s = 0.0;
#pragma unroll
  for (int k = 0; k < C_ / 4; ++k) {
    float4 v = row[k];
    s = fma((double)v.x, (double)v.x, s);
    s = fma((double)v.y, (double)v.y, s);
    s = fma((double)v.z, (double)v.z, s);
    s = fma((double)v.w, (double)v.w, s);
  }
  enorm[code] = (float)s;
  const int nt = code >> 5, lcol = code & 31;
#pragma unroll
  for (int s16 = 0; s16 < 16; ++s16) {
#pragma unroll
    for (int h2 = 0; h2 < 2; ++h2) {
      float4 v0 = row[s16 * 4 + h2 * 2];
      float4 v1 = row[s16 * 4 + h2 * 2 + 1];
      half8 hv;
      hv[0] = (_Float16)v0.x; hv[1] = (_Float16)v0.y;
      hv[2] = (_Float16)v0.z; hv[3] = (_Float16)v0.w;
      hv[4] = (_Float16)v1.x; hv[5] = (_Float16)v1.y;
      hv[6] = (_Float16)v1.z; hv[7] = (_Float16)v1.w;
      ebuf[(nt * 16 + s16) * 64 + h2 * 32 + lcol] = hv;
    }
  }
}

// MFMA VQ: per wave 32 rows x 1024 codes, dot = z_hi.e16 + z_lo.e16 (f16 split).
// A held in VGPRs (128), B streamed from L2-resident prearranged ebuf. No LDS.
__launch_bounds__(256, 2)
__global__ void k_vq(const float* __restrict__ z, const half8* __restrict__ ebuf,
                     const float* __restrict__ enorm, int* __restrict__ idx_i,
                     float* __restrict__ idx_f, int* __restrict__ counts,
                     int* __restrict__ nflag, int* __restrict__ worklist) {
  const int tid = threadIdx.x;
  const int w = tid >> 6;        // wave 0..3
  const int l = tid & 63;
  const int lcol = l & 31;       // A-row slot / B-col slot
  const int h2 = l >> 5;         // k-group
  const int n0 = blockIdx.x * 128;
  const int b = n0 >> 11;
  const int t = (n0 & (T_ - 1)) + w * 32 + lcol;
  const float* zcol = z + (size_t)b * C_ * T_ + t;

  // Load this lane's A column of z once; split fp32 -> hi/lo f16.
  half8 Ah[16], Al[16];
#pragma unroll
  for (int s = 0; s < 16; ++s) {
    half8 hv, lv;
#pragma unroll
    for (int i = 0; i < 8; ++i) {
      float zf = zcol[(size_t)(16 * s + 8 * h2 + i) * T_];
      _Float16 hh = (_Float16)zf;
      hv[i] = hh;
      lv[i] = (_Float16)(zf - (float)hh);
    }
    Ah[s] = hv; Al[s] = lv;
  }

  f32x16 Z;
#pragma unroll
  for (int r = 0; r < 16; ++r) Z[r] = 0.f;

  float b1s[16], b2s[16]; int b1i[16];
#pragma unroll
  for (int r = 0; r < 16; ++r) { b1s[r] = 3.4e38f; b2s[r] = 3.4e38f; b1i[r] = 0; }

  const half8* bp = ebuf + l;
  for (int nt = 0; nt < 32; ++nt) {
    f32x16 ah = Z, al = Z;  // two independent MFMA chains (hi, lo)
#pragma unroll
    for (int s = 0; s < 16; ++s) {
      half8 bf = bp[(nt * 16 + s) * 64];
      ah = __builtin_amdgcn_mfma_f32_32x32x16_f16(Ah[s], bf, ah, 0, 0, 0);
      al = __builtin_amdgcn_mfma_f32_32x32x16_f16(Al[s], bf, al, 0, 0, 0);
    }
    const int codeb = (nt << 5) + lcol;
    const float en = enorm[codeb];
#pragma unroll
    for (int r = 0; r < 16; ++r) {
      float sc = fmaf(-2.f, ah[r] + al[r], en);
      float nb2 = fminf(b2s[r], fmaxf(b1s[r], sc));
      bool lt = sc < b1s[r];              // strict <: codes ascend -> lowest kept
      b2s[r] = nb2;
      b1i[r] = lt ? codeb : b1i[r];
      b1s[r] = fminf(b1s[r], sc);
    }
  }
  // merge top-2 across the 32 code-lanes (masks 1..16 stay within 32-lane half)
#pragma unroll
  for (int m = 1; m < 32; m <<= 1) {
#pragma unroll
    for (int r = 0; r < 16; ++r) {
      float o1 = __shfl_xor(b1s[r], m);
      int oi = __shfl_xor(b1i[r], m);
      float o2 = __shfl_xor(b2s[r], m);
      float hi = fmaxf(b1s[r], o1);
      b2s[r] = fminf(fminf(b2s[r], o2), hi);
      if (o1 < b1s[r] || (o1 == b1s[r] && oi < b1i[r])) { b1s[r] = o1; b1i[r] = oi; }
    }
  }
  if (lcol == 0) {
#pragma unroll
    for (int r = 0; r < 16; ++r) {
      // C/D layout (m74/m101, dtype-independent): row = (r&3) + 8*(r>>2) + 4*h2
      int n = n0 + w * 32 + (r & 3) + ((r >> 2) << 3) + (h2 << 2);
      idx_i[n] = b1i[r];
      idx_f[n] = (float)b1i[r];
      atomicAdd(&counts[b1i[r]], 1);
      if (b2s[r] - b1s[r] < TAU) {
        int p = atomicAdd(nflag, 1);
        if (p < WLCAP) worklist[p] = n;
      }
    }
  }
}

// Re-score flagged rows emulating numpy's fp32 arithmetic:
//   d_j = fl32( fl32(sz + se_j) - fl32(2 * dot_j) ), dot via sequential fp32 FMA,
// argmin with lowest-index tie-break; fix counts when the winner changes.
__global__ void k_repair(const float* __restrict__ z, const float* __restrict__ emb,
                         const float* __restrict__ enorm,
                         const int* __restrict__ nflag, const int* __restrict__ worklist,
                         int* __restrict__ idx_i, float* __restrict__ idx_f,
                         int* __restrict__ counts) {
  __shared__ float zs[C_];
  __shared__ float szf_s;
  __shared__ double wred[4];
  __shared__ float rs[256];
  __shared__ int ri[256];
  int cnt = nflag[0];
  if (cnt > WLCAP) cnt = WLCAP;
  for (int wi = blockIdx.x; wi < cnt; wi += gridDim.x) {
    int n = worklist[wi];
    int b = n >> 11, t = n & (T_ - 1);
    float zv = z[(size_t)b * C_ * T_ + (size_t)threadIdx.x * T_ + t];
    zs[threadIdx.x] = zv;
    double p = (double)zv * (double)zv;
#pragma unroll
    for (int m = 32; m > 0; m >>= 1) p += __shfl_down(p, m);
    if ((threadIdx.x & 63) == 0) wred[threadIdx.x >> 6] = p;
    __syncthreads();
    if (threadIdx.x == 0)
      szf_s = (float)(wred[0] + wred[1] + wred[2] + wred[3]);
    __syncthreads();
    const float szf = szf_s;
    float bd = 3.4e38f; int bi = 1 << 30;
#pragma unroll
    for (int rep = 0; rep < 4; ++rep) {
      int j = rep * 256 + threadIdx.x;
      const float4* er = reinterpret_cast<const float4*>(emb + (size_t)j * C_);
      float acc = 0.f;
#pragma unroll 8
      for (int k4 = 0; k4 < C_ / 4; ++k4) {
        float4 ev = er[k4];
        acc = fmaf(zs[k4 * 4 + 0], ev.x, acc);
        acc = fmaf(zs[k4 * 4 + 1], ev.y, acc);
        acc = fmaf(zs[k4 * 4 + 2], ev.z, acc);
        acc = fmaf(zs[k4 * 4 + 3], ev.w, acc);
      }
      float X = szf + enorm[j];
      float Y = 2.0f * acc;
      float d = X - Y;
      if (d < bd || (d == bd && j < bi)) { bd = d; bi = j; }
    }
    rs[threadIdx.x] = bd; ri[threadIdx.x] = bi;
    __syncthreads();
    for (int o = 128; o > 0; o >>= 1) {
      if (threadIdx.x < o) {
        float os = rs[threadIdx.x + o]; int oi = ri[threadIdx.x + o];
        if (os < rs[threadIdx.x] || (os == rs[threadIdx.x] && oi < ri[threadIdx.x])) {
          rs[threadIdx.x] = os; ri[threadIdx.x] = oi;
        }
      }
      __syncthreads();
    }
    if (threadIdx.x == 0) {
      int old = idx_i[n];
      int nw = ri[0];
      if (nw != old) {
        idx_i[n] = nw; idx_f[n] = (float)nw;
        atomicAdd(&counts[old], -1);
        atomicAdd(&counts[nw], 1);
      }
    }
    __syncthreads();
  }
}

__global__ void k_gather(const float* __restrict__ z, const float* __restrict__ emb,
                         const int* __restrict__ idxv, float* __restrict__ zq,
                         float* __restrict__ sse) {
  int gid = blockIdx.x * blockDim.x + threadIdx.x;
  int i = gid << 2;
  int t = i & (T_ - 1);
  int bc = i >> 11;
  int c = bc & (C_ - 1);
  int b = bc >> 8;
  int n = (b << 11) + t;
  int4 id = *reinterpret_cast<const int4*>(&idxv[n]);
  float4 zv = *reinterpret_cast<const float4*>(&z[i]);
  float4 q;
  q.x = emb[id.x * C_ + c];
  q.y = emb[id.y * C_ + c];
  q.z = emb[id.z * C_ + c];
  q.w = emb[id.w * C_ + c];
  *reinterpret_cast<float4*>(&zq[i]) = q;
  float dx = q.x - zv.x, dy = q.y - zv.y, dz = q.z - zv.z, dw = q.w - zv.w;
  float local = dx * dx + dy * dy + dz * dz + dw * dw;
#pragma unroll
  for (int m = 32; m > 0; m >>= 1) local += __shfl_down(local, m);
  __shared__ float wsum[4];
  if ((threadIdx.x & 63) == 0) wsum[threadIdx.x >> 6] = local;
  __syncthreads();
  if (threadIdx.x == 0) atomicAdd(sse, wsum[0] + wsum[1] + wsum[2] + wsum[3]);
}

__global__ void k_final(const int* __restrict__ counts, const float* __restrict__ sse,
                        float* __restrict__ out_loss, float* __restrict__ out_perp) {
  __shared__ float red[256];
  int tid = threadIdx.x;
  float s = 0.f;
  for (int j = tid; j < NE_; j += 256) {
    float em = (float)counts[j] * (1.0f / (float)N_);
    s += em * logf(em + 1e-10f);
  }
  red[tid] = s;
  __syncthreads();
  for (int o = 128; o > 0; o >>= 1) {
    if (tid < o) red[tid] += red[tid + o];
    __syncthreads();
  }
  if (tid == 0) {
    out_perp[0] = expf(-red[0]);
    out_loss[0] = (0.25f + 1.0f) * sse[0] / (float)NELEM;
  }
}

extern "C" void kernel_launch(void* const* d_in, const int* in_sizes, int n_in,
                              void* d_out, int out_size, void* d_ws, size_t ws_size,
                              hipStream_t stream) {
  const float* z = (const float*)d_in[0];
  const float* emb = (const float*)d_in[1];
  float* out = (float*)d_out;
  float* zq_out = out;
  float* out_loss = out + NELEM;
  float* out_perp = out + NELEM + 1;
  float* out_idx = out + NELEM + 2;

  int* ws_counts = (int*)d_ws;
  float* ws_enorm = (float*)d_ws + 1024;
  float* ws_sse = (float*)d_ws + 2048;
  int* ws_nflag = (int*)d_ws + 2049;
  int* ws_idx = (int*)d_ws + 4608;
  int* ws_worklist = (int*)d_ws + 70144;
  half8* ws_ebuf = (half8*)((float*)d_ws + 98304);

  // zero counts + sse + nflag
  hipMemsetAsync(d_ws, 0, 8224, stream);

  k_prep<<<NE_ / 256, 256, 0, stream>>>(emb, ws_ebuf, ws_enorm);
  k_vq<<<N_ / 128, 256, 0, stream>>>(z, ws_ebuf, ws_enorm, ws_idx, out_idx,
                                     ws_counts, ws_nflag, ws_worklist);
  k_repair<<<2048, 256, 0, stream>>>(z, emb, ws_enorm, ws_nflag, ws_worklist,
                                     ws_idx, out_idx, ws_counts);
  k_gather<<<NELEM / 4 / 256, 256, 0, stream>>>(z, emb, ws_idx, zq_out, ws_sse);
  k_final<<<1, 256, 0, stream>>>(ws_counts, ws_sse, out_loss, out_perp);
}

// Round 5
// 469.682 us; speedup vs baseline: 2.0299x; 1.3788x over previous
//
#include <hip/hip_runtime.h>

#define B_ 32
#define C_ 256
#define T_ 2048
#define N_ 65536      // B_*T_
#define NE_ 1024
#define NELEM 16777216  // B_*C_*T_
#define TAU 1.75e-4f    // repair window: np fp32 quantization (~3.2e-5) + f16-split GEMM noise (~4e-5), 2x margin
#define WLCAP 16384
#define RPB 8           // flagged rows per repair block

typedef _Float16 half8 __attribute__((ext_vector_type(8)));
typedef float f32x16 __attribute__((ext_vector_type(16)));

// d_ws layout (4-byte units):
// [0,1024)        counts (int)
// [1024,2048)     enorm (float, fl32 of fp64-exact ||e||^2)
// [2048]          sse (float)
// [2049]          nflag (int)
// [4608,70144)    idx (int)
// [70144,86528)   worklist (int)
// [98304,229376)  ebuf: e as f16 in MFMA B-fragment order (512 KB)

__global__ void k_prep(const float* __restrict__ emb, half8* __restrict__ ebuf,
                       float* __restrict__ enorm) {
  int code = blockIdx.x * blockDim.x + threadIdx.x;  // 0..1023
  const float4* row = reinterpret_cast<const float4*>(emb + (size_t)code * C_);
  double s = 0.0;
#pragma unroll
  for (int k = 0; k < C_ / 4; ++k) {
    float4 v = row[k];
    s = fma((double)v.x, (double)v.x, s);
    s = fma((double)v.y, (double)v.y, s);
    s = fma((double)v.z, (double)v.z, s);
    s = fma((double)v.w, (double)v.w, s);
  }
  enorm[code] = (float)s;
  const int nt = code >> 5, lcol = code & 31;
#pragma unroll
  for (int s16 = 0; s16 < 16; ++s16) {
#pragma unroll
    for (int h2 = 0; h2 < 2; ++h2) {
      float4 v0 = row[s16 * 4 + h2 * 2];
      float4 v1 = row[s16 * 4 + h2 * 2 + 1];
      half8 hv;
      hv[0] = (_Float16)v0.x; hv[1] = (_Float16)v0.y;
      hv[2] = (_Float16)v0.z; hv[3] = (_Float16)v0.w;
      hv[4] = (_Float16)v1.x; hv[5] = (_Float16)v1.y;
      hv[6] = (_Float16)v1.z; hv[7] = (_Float16)v1.w;
      ebuf[(nt * 16 + s16) * 64 + h2 * 32 + lcol] = hv;
    }
  }
}

// MFMA VQ: per wave 32 rows x 1024 codes, dot = z_hi.e16 + z_lo.e16 (f16 split).
__launch_bounds__(256, 2)
__global__ void k_vq(const float* __restrict__ z, const half8* __restrict__ ebuf,
                     const float* __restrict__ enorm, int* __restrict__ idx_i,
                     float* __restrict__ idx_f, int* __restrict__ counts,
                     int* __restrict__ nflag, int* __restrict__ worklist) {
  const int tid = threadIdx.x;
  const int w = tid >> 6;        // wave 0..3
  const int l = tid & 63;
  const int lcol = l & 31;       // A-row slot / B-col slot
  const int h2 = l >> 5;         // k-group
  const int n0 = blockIdx.x * 128;
  const int b = n0 >> 11;
  const int t = (n0 & (T_ - 1)) + w * 32 + lcol;
  const float* zcol = z + (size_t)b * C_ * T_ + t;

  half8 Ah[16], Al[16];
#pragma unroll
  for (int s = 0; s < 16; ++s) {
    half8 hv, lv;
#pragma unroll
    for (int i = 0; i < 8; ++i) {
      float zf = zcol[(size_t)(16 * s + 8 * h2 + i) * T_];
      _Float16 hh = (_Float16)zf;
      hv[i] = hh;
      lv[i] = (_Float16)(zf - (float)hh);
    }
    Ah[s] = hv; Al[s] = lv;
  }

  f32x16 Z;
#pragma unroll
  for (int r = 0; r < 16; ++r) Z[r] = 0.f;

  float b1s[16], b2s[16]; int b1i[16];
#pragma unroll
  for (int r = 0; r < 16; ++r) { b1s[r] = 3.4e38f; b2s[r] = 3.4e38f; b1i[r] = 0; }

  const half8* bp = ebuf + l;
  for (int nt = 0; nt < 32; ++nt) {
    f32x16 ah = Z, al = Z;
#pragma unroll
    for (int s = 0; s < 16; ++s) {
      half8 bf = bp[(nt * 16 + s) * 64];
      ah = __builtin_amdgcn_mfma_f32_32x32x16_f16(Ah[s], bf, ah, 0, 0, 0);
      al = __builtin_amdgcn_mfma_f32_32x32x16_f16(Al[s], bf, al, 0, 0, 0);
    }
    const int codeb = (nt << 5) + lcol;
    const float en = enorm[codeb];
#pragma unroll
    for (int r = 0; r < 16; ++r) {
      float sc = fmaf(-2.f, ah[r] + al[r], en);
      float nb2 = fminf(b2s[r], fmaxf(b1s[r], sc));
      bool lt = sc < b1s[r];
      b2s[r] = nb2;
      b1i[r] = lt ? codeb : b1i[r];
      b1s[r] = fminf(b1s[r], sc);
    }
  }
#pragma unroll
  for (int m = 1; m < 32; m <<= 1) {
#pragma unroll
    for (int r = 0; r < 16; ++r) {
      float o1 = __shfl_xor(b1s[r], m);
      int oi = __shfl_xor(b1i[r], m);
      float o2 = __shfl_xor(b2s[r], m);
      float hi = fmaxf(b1s[r], o1);
      b2s[r] = fminf(fminf(b2s[r], o2), hi);
      if (o1 < b1s[r] || (o1 == b1s[r] && oi < b1i[r])) { b1s[r] = o1; b1i[r] = oi; }
    }
  }
  if (lcol == 0) {
#pragma unroll
    for (int r = 0; r < 16; ++r) {
      int n = n0 + w * 32 + (r & 3) + ((r >> 2) << 3) + (h2 << 2);
      idx_i[n] = b1i[r];
      idx_f[n] = (float)b1i[r];
      atomicAdd(&counts[b1i[r]], 1);
      if (b2s[r] - b1s[r] < TAU) {
        int p = atomicAdd(nflag, 1);
        if (p < WLCAP) worklist[p] = n;
      }
    }
  }
}

// Re-score flagged rows (batched RPB per block) emulating numpy's fp32 arithmetic:
//   d_j = fl32( fl32(sz + se_j) - fl32(2 * dot_j) ), dot via sequential fp32 FMA
//   over k ascending; argmin with lowest-index tie-break; fix counts on change.
__global__ void k_repair(const float* __restrict__ z, const float* __restrict__ emb,
                         const float* __restrict__ enorm,
                         const int* __restrict__ nflag, const int* __restrict__ worklist,
                         int* __restrict__ idx_i, float* __restrict__ idx_f,
                         int* __restrict__ counts) {
  __shared__ float4 zs4[RPB][C_ / 4];
  __shared__ double wred[4][RPB];
  __shared__ float szf[RPB];
  __shared__ float rs[RPB][256];
  __shared__ int ri[RPB][256];
  const int tid = threadIdx.x;
  int cnt = nflag[0];
  if (cnt > WLCAP) cnt = WLCAP;
  const int nbatch = (cnt + RPB - 1) / RPB;
  for (int batch = blockIdx.x; batch < nbatch; batch += gridDim.x) {
    const int base = batch * RPB;
    double p[RPB];
#pragma unroll
    for (int r = 0; r < RPB; ++r) {
      int wi = base + r;
      int n = worklist[wi < cnt ? wi : base];
      int b = n >> 11, t = n & (T_ - 1);
      float zv = z[(size_t)b * C_ * T_ + (size_t)tid * T_ + t];
      reinterpret_cast<float*>(&zs4[r][0])[tid] = zv;
      p[r] = (double)zv * (double)zv;
    }
#pragma unroll
    for (int m = 32; m > 0; m >>= 1)
#pragma unroll
      for (int r = 0; r < RPB; ++r) p[r] += __shfl_down(p[r], m);
    if ((tid & 63) == 0)
#pragma unroll
      for (int r = 0; r < RPB; ++r) wred[tid >> 6][r] = p[r];
    __syncthreads();
    if (tid < RPB)
      szf[tid] = (float)(wred[0][tid] + wred[1][tid] + wred[2][tid] + wred[3][tid]);
    __syncthreads();

    float bd[RPB]; int bi[RPB];
#pragma unroll
    for (int r = 0; r < RPB; ++r) { bd[r] = 3.4e38f; bi[r] = 1 << 30; }
#pragma unroll
    for (int rep = 0; rep < 4; ++rep) {
      const int j = rep * 256 + tid;  // ascending codes within thread
      const float4* er = reinterpret_cast<const float4*>(emb + (size_t)j * C_);
      float acc[RPB];
#pragma unroll
      for (int r = 0; r < RPB; ++r) acc[r] = 0.f;
#pragma unroll 8
      for (int k4 = 0; k4 < C_ / 4; ++k4) {
        float4 ev = er[k4];
#pragma unroll
        for (int r = 0; r < RPB; ++r) {
          float4 zv = zs4[r][k4];  // broadcast read, conflict-free
          acc[r] = fmaf(zv.x, ev.x, acc[r]);
          acc[r] = fmaf(zv.y, ev.y, acc[r]);
          acc[r] = fmaf(zv.z, ev.z, acc[r]);
          acc[r] = fmaf(zv.w, ev.w, acc[r]);
        }
      }
      const float en = enorm[j];
#pragma unroll
      for (int r = 0; r < RPB; ++r) {
        float X = szf[r] + en;
        float Y = 2.0f * acc[r];
        float d = X - Y;
        if (d < bd[r] || (d == bd[r] && j < bi[r])) { bd[r] = d; bi[r] = j; }
      }
    }
#pragma unroll
    for (int r = 0; r < RPB; ++r) { rs[r][tid] = bd[r]; ri[r][tid] = bi[r]; }
    __syncthreads();
    for (int o = 128; o > 0; o >>= 1) {
      if (tid < o) {
#pragma unroll
        for (int r = 0; r < RPB; ++r) {
          float os = rs[r][tid + o]; int oi = ri[r][tid + o];
          if (os < rs[r][tid] || (os == rs[r][tid] && oi < ri[r][tid])) {
            rs[r][tid] = os; ri[r][tid] = oi;
          }
        }
      }
      __syncthreads();
    }
    if (tid < RPB) {
      int wi = base + tid;
      if (wi < cnt) {
        int n = worklist[wi];
        int old = idx_i[n];
        int nw = ri[tid][0];
        if (nw != old) {
          idx_i[n] = nw; idx_f[n] = (float)nw;
          atomicAdd(&counts[old], -1);
          atomicAdd(&counts[nw], 1);
        }
      }
    }
    __syncthreads();
  }
}

__global__ void k_gather(const float* __restrict__ z, const float* __restrict__ emb,
                         const int* __restrict__ idxv, float* __restrict__ zq,
                         float* __restrict__ sse) {
  int gid = blockIdx.x * blockDim.x + threadIdx.x;
  int i = gid << 2;
  int t = i & (T_ - 1);
  int bc = i >> 11;
  int c = bc & (C_ - 1);
  int b = bc >> 8;
  int n = (b << 11) + t;
  int4 id = *reinterpret_cast<const int4*>(&idxv[n]);
  float4 zv = *reinterpret_cast<const float4*>(&z[i]);
  float4 q;
  q.x = emb[id.x * C_ + c];
  q.y = emb[id.y * C_ + c];
  q.z = emb[id.z * C_ + c];
  q.w = emb[id.w * C_ + c];
  *reinterpret_cast<float4*>(&zq[i]) = q;
  float dx = q.x - zv.x, dy = q.y - zv.y, dz = q.z - zv.z, dw = q.w - zv.w;
  float local = dx * dx + dy * dy + dz * dz + dw * dw;
#pragma unroll
  for (int m = 32; m > 0; m >>= 1) local += __shfl_down(local, m);
  __shared__ float wsum[4];
  if ((threadIdx.x & 63) == 0) wsum[threadIdx.x >> 6] = local;
  __syncthreads();
  if (threadIdx.x == 0) atomicAdd(sse, wsum[0] + wsum[1] + wsum[2] + wsum[3]);
}

__global__ void k_final(const int* __restrict__ counts, const float* __restrict__ sse,
                        float* __restrict__ out_loss, float* __restrict__ out_perp) {
  __shared__ float red[256];
  int tid = threadIdx.x;
  float s = 0.f;
  for (int j = tid; j < NE_; j += 256) {
    float em = (float)counts[j] * (1.0f / (float)N_);
    s += em * logf(em + 1e-10f);
  }
  red[tid] = s;
  __syncthreads();
  for (int o = 128; o > 0; o >>= 1) {
    if (tid < o) red[tid] += red[tid + o];
    __syncthreads();
  }
  if (tid == 0) {
    out_perp[0] = expf(-red[0]);
    out_loss[0] = (0.25f + 1.0f) * sse[0] / (float)NELEM;
  }
}

extern "C" void kernel_launch(void* const* d_in, const int* in_sizes, int n_in,
                              void* d_out, int out_size, void* d_ws, size_t ws_size,
                              hipStream_t stream) {
  const float* z = (const float*)d_in[0];
  const float* emb = (const float*)d_in[1];
  float* out = (float*)d_out;
  float* zq_out = out;
  float* out_loss = out + NELEM;
  float* out_perp = out + NELEM + 1;
  float* out_idx = out + NELEM + 2;

  int* ws_counts = (int*)d_ws;
  float* ws_enorm = (float*)d_ws + 1024;
  float* ws_sse = (float*)d_ws + 2048;
  int* ws_nflag = (int*)d_ws + 2049;
  int* ws_idx = (int*)d_ws + 4608;
  int* ws_worklist = (int*)d_ws + 70144;
  half8* ws_ebuf = (half8*)((float*)d_ws + 98304);

  hipMemsetAsync(d_ws, 0, 8224, stream);

  k_prep<<<NE_ / 256, 256, 0, stream>>>(emb, ws_ebuf, ws_enorm);
  k_vq<<<N_ / 128, 256, 0, stream>>>(z, ws_ebuf, ws_enorm, ws_idx, out_idx,
                                     ws_counts, ws_nflag, ws_worklist);
  k_repair<<<2048, 256, 0, stream>>>(z, emb, ws_enorm, ws_nflag, ws_worklist,
                                     ws_idx, out_idx, ws_counts);
  k_gather<<<NELEM / 4 / 256, 256, 0, stream>>>(z, emb, ws_idx, zq_out, ws_sse);
  k_final<<<1, 256, 0, stream>>>(ws_counts, ws_sse, out_loss, out_perp);
}

// Round 6
// 291.790 us; speedup vs baseline: 3.2675x; 1.6097x over previous
//
#include <hip/hip_runtime.h>

#define B_ 32
#define C_ 256
#define T_ 2048
#define N_ 65536      // B_*T_
#define NE_ 1024
#define NELEM 16777216  // B_*C_*T_
#define TAU 1.75e-4f    // repair window: np fp32 quantization (~3.2e-5) + f16-split GEMM noise (~4e-5), 2x margin
#define WLCAP 16384
#define RPB 8           // flagged rows per repair block

typedef _Float16 half8 __attribute__((ext_vector_type(8)));
typedef float f32x16 __attribute__((ext_vector_type(16)));

// d_ws layout (4-byte units):
// [0,1024)        counts (int)
// [1024,2048)     enorm (float, fl32 of fp64-exact ||e||^2)
// [2048]          sse (float)
// [2049]          nflag (int)
// [4608,70144)    idx (int)
// [70144,86528)   worklist (int)
// [98304,229376)  ebuf: e as f16 in MFMA B-fragment order (512 KB)

__global__ void k_prep(const float* __restrict__ emb, half8* __restrict__ ebuf,
                       float* __restrict__ enorm) {
  int code = blockIdx.x * blockDim.x + threadIdx.x;  // 0..1023
  const float4* row = reinterpret_cast<const float4*>(emb + (size_t)code * C_);
  double s = 0.0;
#pragma unroll
  for (int k = 0; k < C_ / 4; ++k) {
    float4 v = row[k];
    s = fma((double)v.x, (double)v.x, s);
    s = fma((double)v.y, (double)v.y, s);
    s = fma((double)v.z, (double)v.z, s);
    s = fma((double)v.w, (double)v.w, s);
  }
  enorm[code] = (float)s;
  const int nt = code >> 5, lcol = code & 31;
#pragma unroll
  for (int s16 = 0; s16 < 16; ++s16) {
#pragma unroll
    for (int h2 = 0; h2 < 2; ++h2) {
      float4 v0 = row[s16 * 4 + h2 * 2];
      float4 v1 = row[s16 * 4 + h2 * 2 + 1];
      half8 hv;
      hv[0] = (_Float16)v0.x; hv[1] = (_Float16)v0.y;
      hv[2] = (_Float16)v0.z; hv[3] = (_Float16)v0.w;
      hv[4] = (_Float16)v1.x; hv[5] = (_Float16)v1.y;
      hv[6] = (_Float16)v1.z; hv[7] = (_Float16)v1.w;
      ebuf[(nt * 16 + s16) * 64 + h2 * 32 + lcol] = hv;
    }
  }
}

// MFMA VQ: per wave 32 rows x 1024 codes, dot = z_hi.e16 + z_lo.e16 (f16 split).
__launch_bounds__(256, 2)
__global__ void k_vq(const float* __restrict__ z, const half8* __restrict__ ebuf,
                     const float* __restrict__ enorm, int* __restrict__ idx_i,
                     float* __restrict__ idx_f, int* __restrict__ counts,
                     int* __restrict__ nflag, int* __restrict__ worklist) {
  const int tid = threadIdx.x;
  const int w = tid >> 6;        // wave 0..3
  const int l = tid & 63;
  const int lcol = l & 31;       // A-row slot / B-col slot
  const int h2 = l >> 5;         // k-group
  const int n0 = blockIdx.x * 128;
  const int b = n0 >> 11;
  const int t = (n0 & (T_ - 1)) + w * 32 + lcol;
  const float* zcol = z + (size_t)b * C_ * T_ + t;

  half8 Ah[16], Al[16];
#pragma unroll
  for (int s = 0; s < 16; ++s) {
    half8 hv, lv;
#pragma unroll
    for (int i = 0; i < 8; ++i) {
      float zf = zcol[(size_t)(16 * s + 8 * h2 + i) * T_];
      _Float16 hh = (_Float16)zf;
      hv[i] = hh;
      lv[i] = (_Float16)(zf - (float)hh);
    }
    Ah[s] = hv; Al[s] = lv;
  }

  f32x16 Z;
#pragma unroll
  for (int r = 0; r < 16; ++r) Z[r] = 0.f;

  float b1s[16], b2s[16]; int b1i[16];
#pragma unroll
  for (int r = 0; r < 16; ++r) { b1s[r] = 3.4e38f; b2s[r] = 3.4e38f; b1i[r] = 0; }

  const half8* bp = ebuf + l;
  for (int nt = 0; nt < 32; ++nt) {
    f32x16 ah = Z, al = Z;
#pragma unroll
    for (int s = 0; s < 16; ++s) {
      half8 bf = bp[(nt * 16 + s) * 64];
      ah = __builtin_amdgcn_mfma_f32_32x32x16_f16(Ah[s], bf, ah, 0, 0, 0);
      al = __builtin_amdgcn_mfma_f32_32x32x16_f16(Al[s], bf, al, 0, 0, 0);
    }
    const int codeb = (nt << 5) + lcol;
    const float en = enorm[codeb];
#pragma unroll
    for (int r = 0; r < 16; ++r) {
      float sc = fmaf(-2.f, ah[r] + al[r], en);
      float nb2 = fminf(b2s[r], fmaxf(b1s[r], sc));
      bool lt = sc < b1s[r];
      b2s[r] = nb2;
      b1i[r] = lt ? codeb : b1i[r];
      b1s[r] = fminf(b1s[r], sc);
    }
  }
#pragma unroll
  for (int m = 1; m < 32; m <<= 1) {
#pragma unroll
    for (int r = 0; r < 16; ++r) {
      float o1 = __shfl_xor(b1s[r], m);
      int oi = __shfl_xor(b1i[r], m);
      float o2 = __shfl_xor(b2s[r], m);
      float hi = fmaxf(b1s[r], o1);
      b2s[r] = fminf(fminf(b2s[r], o2), hi);
      if (o1 < b1s[r] || (o1 == b1s[r] && oi < b1i[r])) { b1s[r] = o1; b1i[r] = oi; }
    }
  }
  if (lcol == 0) {
#pragma unroll
    for (int r = 0; r < 16; ++r) {
      int n = n0 + w * 32 + (r & 3) + ((r >> 2) << 3) + (h2 << 2);
      idx_i[n] = b1i[r];
      idx_f[n] = (float)b1i[r];
      atomicAdd(&counts[b1i[r]], 1);
      if (b2s[r] - b1s[r] < TAU) {
        int p = atomicAdd(nflag, 1);
        if (p < WLCAP) worklist[p] = n;
      }
    }
  }
}

// Re-score flagged rows (batched RPB per block) emulating numpy's fp32 arithmetic.
__global__ void k_repair(const float* __restrict__ z, const float* __restrict__ emb,
                         const float* __restrict__ enorm,
                         const int* __restrict__ nflag, const int* __restrict__ worklist,
                         int* __restrict__ idx_i, float* __restrict__ idx_f,
                         int* __restrict__ counts) {
  __shared__ float4 zs4[RPB][C_ / 4];
  __shared__ double wred[4][RPB];
  __shared__ float szf[RPB];
  __shared__ float rs[RPB][256];
  __shared__ int ri[RPB][256];
  const int tid = threadIdx.x;
  int cnt = nflag[0];
  if (cnt > WLCAP) cnt = WLCAP;
  const int nbatch = (cnt + RPB - 1) / RPB;
  for (int batch = blockIdx.x; batch < nbatch; batch += gridDim.x) {
    const int base = batch * RPB;
    double p[RPB];
#pragma unroll
    for (int r = 0; r < RPB; ++r) {
      int wi = base + r;
      int n = worklist[wi < cnt ? wi : base];
      int b = n >> 11, t = n & (T_ - 1);
      float zv = z[(size_t)b * C_ * T_ + (size_t)tid * T_ + t];
      reinterpret_cast<float*>(&zs4[r][0])[tid] = zv;
      p[r] = (double)zv * (double)zv;
    }
#pragma unroll
    for (int m = 32; m > 0; m >>= 1)
#pragma unroll
      for (int r = 0; r < RPB; ++r) p[r] += __shfl_down(p[r], m);
    if ((tid & 63) == 0)
#pragma unroll
      for (int r = 0; r < RPB; ++r) wred[tid >> 6][r] = p[r];
    __syncthreads();
    if (tid < RPB)
      szf[tid] = (float)(wred[0][tid] + wred[1][tid] + wred[2][tid] + wred[3][tid]);
    __syncthreads();

    float bd[RPB]; int bi[RPB];
#pragma unroll
    for (int r = 0; r < RPB; ++r) { bd[r] = 3.4e38f; bi[r] = 1 << 30; }
#pragma unroll
    for (int rep = 0; rep < 4; ++rep) {
      const int j = rep * 256 + tid;
      const float4* er = reinterpret_cast<const float4*>(emb + (size_t)j * C_);
      float acc[RPB];
#pragma unroll
      for (int r = 0; r < RPB; ++r) acc[r] = 0.f;
#pragma unroll 8
      for (int k4 = 0; k4 < C_ / 4; ++k4) {
        float4 ev = er[k4];
#pragma unroll
        for (int r = 0; r < RPB; ++r) {
          float4 zv = zs4[r][k4];
          acc[r] = fmaf(zv.x, ev.x, acc[r]);
          acc[r] = fmaf(zv.y, ev.y, acc[r]);
          acc[r] = fmaf(zv.z, ev.z, acc[r]);
          acc[r] = fmaf(zv.w, ev.w, acc[r]);
        }
      }
      const float en = enorm[j];
#pragma unroll
      for (int r = 0; r < RPB; ++r) {
        float X = szf[r] + en;
        float Y = 2.0f * acc[r];
        float d = X - Y;
        if (d < bd[r] || (d == bd[r] && j < bi[r])) { bd[r] = d; bi[r] = j; }
      }
    }
#pragma unroll
    for (int r = 0; r < RPB; ++r) { rs[r][tid] = bd[r]; ri[r][tid] = bi[r]; }
    __syncthreads();
    for (int o = 128; o > 0; o >>= 1) {
      if (tid < o) {
#pragma unroll
        for (int r = 0; r < RPB; ++r) {
          float os = rs[r][tid + o]; int oi = ri[r][tid + o];
          if (os < rs[r][tid] || (os == rs[r][tid] && oi < ri[r][tid])) {
            rs[r][tid] = os; ri[r][tid] = oi;
          }
        }
      }
      __syncthreads();
    }
    if (tid < RPB) {
      int wi = base + tid;
      if (wi < cnt) {
        int n = worklist[wi];
        int old = idx_i[n];
        int nw = ri[tid][0];
        if (nw != old) {
          idx_i[n] = nw; idx_f[n] = (float)nw;
          atomicAdd(&counts[old], -1);
          atomicAdd(&counts[nw], 1);
        }
      }
    }
    __syncthreads();
  }
}

// Tiled gather: per block a 32t x 256c tile of one batch. emb rows loaded
// coalesced (float4) into an LDS transpose tile (pitch 260 -> <=4-way banks),
// then t-contiguous coalesced write-out fused with SSE.
__launch_bounds__(256, 4)
__global__ void k_gather(const float* __restrict__ z, const float* __restrict__ emb,
                         const int* __restrict__ idxv, float* __restrict__ zq,
                         float* __restrict__ sse) {
  __shared__ int ids[32];
  __shared__ float tile[32 * 260];
  __shared__ float wsum[4];
  const int tid = threadIdx.x;
  const int blk = blockIdx.x;
  const int b = blk >> 6;
  const int t0 = (blk & 63) << 5;
  const int n0 = (b << 11) + t0;
  if (tid < 32) ids[tid] = idxv[n0 + tid];
  __syncthreads();
  const int r = tid & 31;   // t within tile
  const int q = tid >> 5;   // c-quarter 0..7 (32 c each)
  {
    const float4* er = reinterpret_cast<const float4*>(emb) + ((size_t)ids[r] << 6) + (q << 3);
    float4* dst = reinterpret_cast<float4*>(&tile[r * 260 + (q << 5)]);
#pragma unroll
    for (int j = 0; j < 8; ++j) dst[j] = er[j];
  }
  __syncthreads();
  float local = 0.f;
  const size_t base = (((size_t)b << 8) << 11) + t0;  // b*256*2048 + t0
#pragma unroll 8
  for (int it = 0; it < 32; ++it) {
    const int c = (it << 3) + q;
    const float qv = tile[r * 260 + c];
    const size_t g = base + ((size_t)c << 11) + r;
    const float zv = z[g];
    zq[g] = qv;
    const float d = qv - zv;
    local = fmaf(d, d, local);
  }
#pragma unroll
  for (int m = 32; m > 0; m >>= 1) local += __shfl_down(local, m);
  if ((tid & 63) == 0) wsum[tid >> 6] = local;
  __syncthreads();
  if (tid == 0) atomicAdd(sse, wsum[0] + wsum[1] + wsum[2] + wsum[3]);
}

__global__ void k_final(const int* __restrict__ counts, const float* __restrict__ sse,
                        float* __restrict__ out_loss, float* __restrict__ out_perp) {
  __shared__ float red[256];
  int tid = threadIdx.x;
  float s = 0.f;
  for (int j = tid; j < NE_; j += 256) {
    float em = (float)counts[j] * (1.0f / (float)N_);
    s += em * logf(em + 1e-10f);
  }
  red[tid] = s;
  __syncthreads();
  for (int o = 128; o > 0; o >>= 1) {
    if (tid < o) red[tid] += red[tid + o];
    __syncthreads();
  }
  if (tid == 0) {
    out_perp[0] = expf(-red[0]);
    out_loss[0] = (0.25f + 1.0f) * sse[0] / (float)NELEM;
  }
}

extern "C" void kernel_launch(void* const* d_in, const int* in_sizes, int n_in,
                              void* d_out, int out_size, void* d_ws, size_t ws_size,
                              hipStream_t stream) {
  const float* z = (const float*)d_in[0];
  const float* emb = (const float*)d_in[1];
  float* out = (float*)d_out;
  float* zq_out = out;
  float* out_loss = out + NELEM;
  float* out_perp = out + NELEM + 1;
  float* out_idx = out + NELEM + 2;

  int* ws_counts = (int*)d_ws;
  float* ws_enorm = (float*)d_ws + 1024;
  float* ws_sse = (float*)d_ws + 2048;
  int* ws_nflag = (int*)d_ws + 2049;
  int* ws_idx = (int*)d_ws + 4608;
  int* ws_worklist = (int*)d_ws + 70144;
  half8* ws_ebuf = (half8*)((float*)d_ws + 98304);

  hipMemsetAsync(d_ws, 0, 8224, stream);

  k_prep<<<NE_ / 256, 256, 0, stream>>>(emb, ws_ebuf, ws_enorm);
  k_vq<<<N_ / 128, 256, 0, stream>>>(z, ws_ebuf, ws_enorm, ws_idx, out_idx,
                                     ws_counts, ws_nflag, ws_worklist);
  k_repair<<<2048, 256, 0, stream>>>(z, emb, ws_enorm, ws_nflag, ws_worklist,
                                     ws_idx, out_idx, ws_counts);
  k_gather<<<2048, 256, 0, stream>>>(z, emb, ws_idx, zq_out, ws_sse);
  k_final<<<1, 256, 0, stream>>>(ws_counts, ws_sse, out_loss, out_perp);
}